// Round 11
// baseline (819.089 us; speedup 1.0000x reference)
//
#include <hip/hip_runtime.h>

// Max-unpooling scatter-add, hist-free single-level radix (512 buckets):
// LDS batch-sort + GLOBAL ATOMIC cursor allocation into fixed-capacity
// bucket regions, then merged accumulate (pairs in regs, 8 x 128 KB LDS
// sweeps). ind/x read exactly once; no histogram prepass, no scans.
//   out = zeros(total); out[ind[i]] += x[i]
// N = 2^25 pairs, OUT = 2^27 floats (536.9 MB).
//
// Cursor atomics: 512 buckets x 2048 batches = 1.05M atomicAdds on 512 hot
// L2-resident addresses -> ~5% of the measured 19.4 G/s device-atomic cap
// (vs 33.5M random atomics in the naive kernel). Allocation order is
// nondeterministic -> fp summation order varies per run (rounding only).

typedef float    f32x4 __attribute__((ext_vector_type(4)));
typedef int      i32x4 __attribute__((ext_vector_type(4)));
typedef unsigned u32x2 __attribute__((ext_vector_type(2)));

#define N_TOT   (1 << 25)     // input pairs
#define OUT_TOT (1 << 27)     // output floats
#define T1      1024          // scatter tiles
#define PT      (N_TOT / T1)  // 32768 pairs/tile
#define PT4     (PT / 4)      // 8192 vec4/tile
#define NB1     512           // buckets
#define CSH     18            // bucket = idx >> 18 (window 2^18 floats = 1 MB)
#define CAP     73728         // per-bucket capacity (mean 65536 + 32 sigma) = 72*1024
#define SSH     15            // sweep = (idx >> 15) & 7
#define NSUB    8
#define WFL     32768         // floats per sweep window (128 KB LDS)
#define BATCH   16384         // pairs per sort batch (128 KB LDS sbuf)
#define KREG    72            // pairs/thread in k_waccum (1024 thr: CAP exactly)

// ---- K1: scatter with LDS batch-sort + atomic segment allocation ----
__global__ __launch_bounds__(1024) void k_scatter(const float* __restrict__ x,
                                                  const int* __restrict__ ind,
                                                  unsigned* __restrict__ gcur,
                                                  u32x2* __restrict__ P1) {
  __shared__ u32x2    sbuf[BATCH];                        // 128 KB
  __shared__ unsigned hist[NB1], sbase[NB1], alloc[NB1];  // 6 KB
  const int t = blockIdx.x;
  const i32x4* pi = reinterpret_cast<const i32x4*>(ind) + (size_t)t * PT4;
  const f32x4* pv = reinterpret_cast<const f32x4*>(x)  + (size_t)t * PT4;

  // Prefetch both batches up-front (1 block/CU: overlap global reads with
  // batch-0's LDS sort + stores). Inputs are read-once -> non-temporal.
  i32x4 idx[2][4];
  f32x4 val[2][4];
  #pragma unroll
  for (int bt = 0; bt < 2; ++bt) {
    const int v0 = bt * (BATCH / 4);
    #pragma unroll
    for (int q = 0; q < 4; ++q) {
      idx[bt][q] = __builtin_nontemporal_load(pi + v0 + q * 1024 + threadIdx.x);
      val[bt][q] = __builtin_nontemporal_load(pv + v0 + q * 1024 + threadIdx.x);
    }
  }

  #pragma unroll
  for (int bt = 0; bt < 2; ++bt) {
    if (threadIdx.x < NB1) hist[threadIdx.x] = 0;
    __syncthreads();
    unsigned r[16];
    #pragma unroll
    for (int q = 0; q < 4; ++q) {
      r[4 * q + 0] = atomicAdd(&hist[(unsigned)idx[bt][q].x >> CSH], 1u);
      r[4 * q + 1] = atomicAdd(&hist[(unsigned)idx[bt][q].y >> CSH], 1u);
      r[4 * q + 2] = atomicAdd(&hist[(unsigned)idx[bt][q].z >> CSH], 1u);
      r[4 * q + 3] = atomicAdd(&hist[(unsigned)idx[bt][q].w >> CSH], 1u);
    }
    __syncthreads();
    // Allocate this batch's per-bucket segments (1 global atomic/bucket).
    // Issued first so the atomic latency hides under the scan + sbuf phases.
    if (threadIdx.x < NB1)
      alloc[threadIdx.x] = atomicAdd(&gcur[threadIdx.x], hist[threadIdx.x]);
    if (threadIdx.x < 64) {   // exclusive scan of hist[512]: 8 entries/lane
      const unsigned lane = threadIdx.x;
      unsigned h[8], sum = 0;
      #pragma unroll
      for (int j = 0; j < 8; ++j) { h[j] = hist[8 * lane + j]; sum += h[j]; }
      unsigned inc = sum;
      for (int off = 1; off < 64; off <<= 1) {
        unsigned o = __shfl_up(inc, off, 64);
        if (lane >= (unsigned)off) inc += o;
      }
      unsigned exc = inc - sum;
      #pragma unroll
      for (int j = 0; j < 8; ++j) { sbase[8 * lane + j] = exc; exc += h[j]; }
    }
    __syncthreads();
    #pragma unroll
    for (int q = 0; q < 4; ++q) {
      sbuf[sbase[(unsigned)idx[bt][q].x >> CSH] + r[4 * q + 0]] =
          (u32x2){__float_as_uint(val[bt][q].x), (unsigned)idx[bt][q].x};
      sbuf[sbase[(unsigned)idx[bt][q].y >> CSH] + r[4 * q + 1]] =
          (u32x2){__float_as_uint(val[bt][q].y), (unsigned)idx[bt][q].y};
      sbuf[sbase[(unsigned)idx[bt][q].z >> CSH] + r[4 * q + 2]] =
          (u32x2){__float_as_uint(val[bt][q].z), (unsigned)idx[bt][q].z};
      sbuf[sbase[(unsigned)idx[bt][q].w >> CSH] + r[4 * q + 3]] =
          (u32x2){__float_as_uint(val[bt][q].w), (unsigned)idx[bt][q].w};
    }
    __syncthreads();
    #pragma unroll
    for (int k = 0; k < BATCH / 1024; ++k) {   // 16 coalesced segment stores
      unsigned j = (unsigned)(k * 1024 + threadIdx.x);
      u32x2 q = sbuf[j];
      unsigned b = q.y >> CSH;
      unsigned pos = alloc[b] + (j - sbase[b]);
      if (pos < CAP)   // statistically impossible overflow; guard OOB anyway
        P1[(size_t)b * CAP + pos] = q;
    }
    __syncthreads();
  }
}

// ---- K2: merged accumulate. Pairs in regs, 8 x 128 KB LDS sweeps ----
__global__ __launch_bounds__(1024) void k_waccum(const u32x2* __restrict__ P1,
                                                 const unsigned* __restrict__ gcur,
                                                 float* __restrict__ out) {
  __shared__ float w[WFL];   // 128 KB
  const int c = blockIdx.x;
  const unsigned len = min(gcur[c], (unsigned)CAP);
  const u32x2* P = P1 + (size_t)c * CAP;
  u32x2 p[KREG];
  #pragma unroll
  for (int k = 0; k < KREG; ++k) {
    unsigned j = (unsigned)(k * 1024) + threadIdx.x;
    p[k] = (j < len) ? P[j]
                     : (u32x2){0u, 0xFFFFFFFFu};  // sentinel: never matches a sweep
  }
  f32x4* w4 = reinterpret_cast<f32x4*>(w);
  for (int sub = 0; sub < NSUB; ++sub) {
    for (int i = threadIdx.x; i < WFL / 4; i += 1024) w4[i] = (f32x4){0.f, 0.f, 0.f, 0.f};
    __syncthreads();
    #pragma unroll
    for (int k = 0; k < KREG; ++k) {
      // sentinel has sweep bits = 7 but bucket bits mismatched; use full check:
      if ((p[k].y >> SSH) == (((unsigned)c << 3) | (unsigned)sub))
        atomicAdd(&w[p[k].y & (WFL - 1)], __uint_as_float(p[k].x));  // ds_add_f32
    }
    __syncthreads();
    f32x4* o = reinterpret_cast<f32x4*>(out + ((size_t)c << CSH) + ((size_t)sub << SSH));
    for (int i = threadIdx.x; i < WFL / 4; i += 1024)
      __builtin_nontemporal_store(w4[i], o + i);
    __syncthreads();
  }
}

// ---- Fallback: plain atomic scatter (measured ~1.77 ms) ----
__global__ __launch_bounds__(256) void unpool_scatter_kernel(
    const float* __restrict__ x, const int* __restrict__ ind,
    float* __restrict__ out, int n4) {
  int i = blockIdx.x * blockDim.x + threadIdx.x;
  if (i >= n4) return;
  f32x4 v  = reinterpret_cast<const f32x4*>(x)[i];
  i32x4 id = reinterpret_cast<const i32x4*>(ind)[i];
  unsafeAtomicAdd(&out[id.x], v.x);
  unsafeAtomicAdd(&out[id.y], v.y);
  unsafeAtomicAdd(&out[id.z], v.z);
  unsafeAtomicAdd(&out[id.w], v.w);
}

extern "C" void kernel_launch(void* const* d_in, const int* in_sizes, int n_in,
                              void* d_out, int out_size, void* d_ws, size_t ws_size,
                              hipStream_t stream) {
  const float* x   = (const float*)d_in[0];
  const int*   ind = (const int*)d_in[1];
  float*       out = (float*)d_out;
  const int n = in_sizes[0];

  // ws layout: gcur[512] | P1 (512 x CAP x 8 B = 302 MB)
  const size_t szG  = ((size_t)NB1 * sizeof(unsigned) + 255) & ~(size_t)255;
  const size_t szP1 = (size_t)NB1 * CAP * sizeof(u32x2);
  const size_t need = szG + szP1;

  const bool shape_ok = (n == N_TOT) && (out_size == OUT_TOT);

  if (!shape_ok || ws_size < need) {
    (void)hipMemsetAsync(d_out, 0, (size_t)out_size * sizeof(float), stream);
    const int n4 = n / 4;
    unpool_scatter_kernel<<<(n4 + 255) / 256, 256, 0, stream>>>(x, ind, out, n4);
    return;
  }

  char* ws = (char*)d_ws;
  unsigned* gcur = (unsigned*)ws;
  u32x2*    P1   = (u32x2*)(ws + szG);

  (void)hipMemsetAsync(gcur, 0, (size_t)NB1 * sizeof(unsigned), stream);
  k_scatter<<<T1,  1024, 0, stream>>>(x, ind, gcur, P1);
  k_waccum <<<NB1, 1024, 0, stream>>>(P1, gcur, out);
  // Output fully covered by dense windows -> no memset of d_out needed.
}

// Round 12
// 378.986 us; speedup vs baseline: 2.1613x; 2.1613x over previous
//
#include <hip/hip_runtime.h>

// Max-unpooling scatter-add, hist-free radix (1024 buckets): LDS batch-sort
// + global atomic cursor allocation into fixed-capacity bucket regions, then
// merged accumulate with pairs held in REGISTERS (512 thr x 72 pairs = 144
// VGPR, fits the 256-VGPR budget at 2 waves/SIMD -> NO SPILL, unlike R11
// where 1024 thr capped VGPRs at 64 and p[] spilled to scratch: FETCH 1.69GB).
//   out = zeros(total); out[ind[i]] += x[i]
// N = 2^25 pairs, OUT = 2^27 floats (536.9 MB).

typedef float    f32x4 __attribute__((ext_vector_type(4)));
typedef int      i32x4 __attribute__((ext_vector_type(4)));
typedef unsigned u32x2 __attribute__((ext_vector_type(2)));

#define N_TOT   (1 << 25)     // input pairs
#define OUT_TOT (1 << 27)     // output floats
#define T1      1024          // scatter tiles
#define PT      (N_TOT / T1)  // 32768 pairs/tile
#define PT4     (PT / 4)      // 8192 vec4/tile
#define NB1     1024          // buckets
#define CSH     17            // bucket = idx >> 17 (window 2^17 floats = 512 KB)
#define CAP     36864         // per-bucket capacity (mean 32768 + 22 sigma)
#define SSH     15            // sweep = (idx >> 15) & 3
#define NSUB    4
#define WFL     32768         // floats per sweep window (128 KB LDS)
#define BATCH   16384         // pairs per sort batch (128 KB LDS sbuf)
#define KREG    72            // pairs/thread in k_waccum (512 thr: CAP exactly)

// ---- K1: scatter with LDS batch-sort + atomic segment allocation ----
__global__ __launch_bounds__(1024) void k_scatter(const float* __restrict__ x,
                                                  const int* __restrict__ ind,
                                                  unsigned* __restrict__ gcur,
                                                  u32x2* __restrict__ P1) {
  __shared__ u32x2    sbuf[BATCH];                        // 128 KB
  __shared__ unsigned hist[NB1], sbase[NB1], alloc[NB1];  // 12 KB
  const int t = blockIdx.x;
  const i32x4* pi = reinterpret_cast<const i32x4*>(ind) + (size_t)t * PT4;
  const f32x4* pv = reinterpret_cast<const f32x4*>(x)  + (size_t)t * PT4;

  for (int bt = 0; bt < 2; ++bt) {
    const int v0 = bt * (BATCH / 4);
    i32x4 idx[4];
    f32x4 val[4];
    #pragma unroll
    for (int q = 0; q < 4; ++q) {
      idx[q] = __builtin_nontemporal_load(pi + v0 + q * 1024 + threadIdx.x);
      val[q] = __builtin_nontemporal_load(pv + v0 + q * 1024 + threadIdx.x);
    }
    hist[threadIdx.x] = 0;
    __syncthreads();
    unsigned r[16];
    #pragma unroll
    for (int q = 0; q < 4; ++q) {
      r[4 * q + 0] = atomicAdd(&hist[(unsigned)idx[q].x >> CSH], 1u);
      r[4 * q + 1] = atomicAdd(&hist[(unsigned)idx[q].y >> CSH], 1u);
      r[4 * q + 2] = atomicAdd(&hist[(unsigned)idx[q].z >> CSH], 1u);
      r[4 * q + 3] = atomicAdd(&hist[(unsigned)idx[q].w >> CSH], 1u);
    }
    __syncthreads();
    // Allocate this batch's per-bucket segments: 1 global atomic/bucket on
    // 1024 hot (L2-resident) addresses. Latency hides under the scan.
    alloc[threadIdx.x] = atomicAdd(&gcur[threadIdx.x], hist[threadIdx.x]);
    if (threadIdx.x < 64) {   // exclusive scan of hist[1024]: 16 entries/lane
      const unsigned lane = threadIdx.x;
      unsigned h[16], sum = 0;
      #pragma unroll
      for (int j = 0; j < 16; ++j) { h[j] = hist[16 * lane + j]; sum += h[j]; }
      unsigned inc = sum;
      for (int off = 1; off < 64; off <<= 1) {
        unsigned o = __shfl_up(inc, off, 64);
        if (lane >= (unsigned)off) inc += o;
      }
      unsigned exc = inc - sum;
      #pragma unroll
      for (int j = 0; j < 16; ++j) { sbase[16 * lane + j] = exc; exc += h[j]; }
    }
    __syncthreads();
    #pragma unroll
    for (int q = 0; q < 4; ++q) {
      sbuf[sbase[(unsigned)idx[q].x >> CSH] + r[4 * q + 0]] =
          (u32x2){__float_as_uint(val[q].x), (unsigned)idx[q].x};
      sbuf[sbase[(unsigned)idx[q].y >> CSH] + r[4 * q + 1]] =
          (u32x2){__float_as_uint(val[q].y), (unsigned)idx[q].y};
      sbuf[sbase[(unsigned)idx[q].z >> CSH] + r[4 * q + 2]] =
          (u32x2){__float_as_uint(val[q].z), (unsigned)idx[q].z};
      sbuf[sbase[(unsigned)idx[q].w >> CSH] + r[4 * q + 3]] =
          (u32x2){__float_as_uint(val[q].w), (unsigned)idx[q].w};
    }
    __syncthreads();
    #pragma unroll
    for (int k = 0; k < BATCH / 1024; ++k) {   // 16 coalesced segment stores
      unsigned j = (unsigned)(k * 1024 + threadIdx.x);
      u32x2 q = sbuf[j];
      unsigned b = q.y >> CSH;
      unsigned pos = alloc[b] + (j - sbase[b]);
      if (pos < CAP)   // statistically impossible overflow; guard OOB anyway
        P1[(size_t)b * CAP + pos] = q;
    }
    __syncthreads();
  }
}

// ---- K2: merged accumulate. Pairs in regs (no spill), 4 x 128 KB sweeps ----
__global__ __launch_bounds__(512, 2) void k_waccum(const u32x2* __restrict__ P1,
                                                   const unsigned* __restrict__ gcur,
                                                   float* __restrict__ out) {
  __shared__ float w[WFL];   // 128 KB
  const int c = blockIdx.x;
  const unsigned len = min(gcur[c], (unsigned)CAP);
  const u32x2* P = P1 + (size_t)c * CAP;
  u32x2 p[KREG];             // 144 VGPRs @ 512 thr (256-VGPR budget) - no spill
  #pragma unroll
  for (int k = 0; k < KREG; ++k) {
    unsigned j = (unsigned)(k * 512) + threadIdx.x;
    p[k] = (j < len) ? __builtin_nontemporal_load(P + j)
                     : (u32x2){0u, 0xFFFFFFFFu};  // sentinel: matches no sweep
  }
  f32x4* w4 = reinterpret_cast<f32x4*>(w);
  for (int sub = 0; sub < NSUB; ++sub) {
    const unsigned key = ((unsigned)c << 2) | (unsigned)sub;  // idx>>SSH value
    for (int i = threadIdx.x; i < WFL / 4; i += 512) w4[i] = (f32x4){0.f, 0.f, 0.f, 0.f};
    __syncthreads();
    #pragma unroll
    for (int k = 0; k < KREG; ++k) {
      if ((p[k].y >> SSH) == key)
        atomicAdd(&w[p[k].y & (WFL - 1)], __uint_as_float(p[k].x));  // ds_add_f32
    }
    __syncthreads();
    f32x4* o = reinterpret_cast<f32x4*>(out + ((size_t)c << CSH) + ((size_t)sub << SSH));
    for (int i = threadIdx.x; i < WFL / 4; i += 512)
      __builtin_nontemporal_store(w4[i], o + i);
    __syncthreads();
  }
}

// ---- Fallback: plain atomic scatter (measured ~1.77 ms) ----
__global__ __launch_bounds__(256) void unpool_scatter_kernel(
    const float* __restrict__ x, const int* __restrict__ ind,
    float* __restrict__ out, int n4) {
  int i = blockIdx.x * blockDim.x + threadIdx.x;
  if (i >= n4) return;
  f32x4 v  = reinterpret_cast<const f32x4*>(x)[i];
  i32x4 id = reinterpret_cast<const i32x4*>(ind)[i];
  unsafeAtomicAdd(&out[id.x], v.x);
  unsafeAtomicAdd(&out[id.y], v.y);
  unsafeAtomicAdd(&out[id.z], v.z);
  unsafeAtomicAdd(&out[id.w], v.w);
}

extern "C" void kernel_launch(void* const* d_in, const int* in_sizes, int n_in,
                              void* d_out, int out_size, void* d_ws, size_t ws_size,
                              hipStream_t stream) {
  const float* x   = (const float*)d_in[0];
  const int*   ind = (const int*)d_in[1];
  float*       out = (float*)d_out;
  const int n = in_sizes[0];

  // ws layout: gcur[1024] | P1 (1024 x CAP x 8 B = 302 MB)
  const size_t szG  = ((size_t)NB1 * sizeof(unsigned) + 255) & ~(size_t)255;
  const size_t szP1 = (size_t)NB1 * CAP * sizeof(u32x2);
  const size_t need = szG + szP1;

  const bool shape_ok = (n == N_TOT) && (out_size == OUT_TOT);

  if (!shape_ok || ws_size < need) {
    (void)hipMemsetAsync(d_out, 0, (size_t)out_size * sizeof(float), stream);
    const int n4 = n / 4;
    unpool_scatter_kernel<<<(n4 + 255) / 256, 256, 0, stream>>>(x, ind, out, n4);
    return;
  }

  char* ws = (char*)d_ws;
  unsigned* gcur = (unsigned*)ws;
  u32x2*    P1   = (u32x2*)(ws + szG);

  (void)hipMemsetAsync(gcur, 0, (size_t)NB1 * sizeof(unsigned), stream);
  k_scatter<<<T1,  1024, 0, stream>>>(x, ind, gcur, P1);
  k_waccum <<<NB1,  512, 0, stream>>>(P1, gcur, out);
  // Output fully covered by dense windows -> no memset of d_out needed.
}